// Round 6
// baseline (5330.127 us; speedup 1.0000x reference)
//
#include <hip/hip_runtime.h>
#include <hip/hip_bf16.h>
#include <stdint.h>

// ---------------- problem dims ----------------
#define BB   64
#define TT   511
#define SS   512
#define DD   500
#define KXP  512          // padded input dim for layer-0 input GEMM
#define HG   384
#define G4   1536
#define HE   64
#define E4   256
#define NSEQ (BB*SS)      // 32768

typedef __hip_bfloat16 bf16;
typedef float  floatx4 __attribute__((ext_vector_type(4)));
typedef int    intx4   __attribute__((ext_vector_type(4)));
typedef __bf16 bfrag8  __attribute__((ext_vector_type(8)));

// v_mfma_f32_16x16x32_bf16 fragment layout (gfx950):
//   A: lane l holds A[l&15][8*(l>>4)+i]      (16B contiguous along K, A stored [M][K])
//   B: lane l holds W[n=l&15][8*(l>>4)+i]    (weights stored [N][K] = torch [out][in])
//   D: lane l, reg r holds D[4*(l>>4)+r][l&15]
static __device__ __forceinline__ floatx4 MFMA16(bfrag8 a, bfrag8 b, floatx4 c){
  return __builtin_amdgcn_mfma_f32_16x16x32_bf16(a, b, c, 0, 0, 0);
}
static __device__ __forceinline__ float sigm_(float x){ return 1.f/(1.f + __expf(-x)); }
static __device__ __forceinline__ float tanh_(float x){
  x = fminf(fmaxf(x, -15.f), 15.f);
  float e = __expf(2.f*x);
  return (e - 1.f)/(e + 1.f);
}
// per-lane gate activation: sigm for i,f,o; tanh via 2*sigm(2x)-1 for g
static __device__ __forceinline__ float actv(float x, bool isg){
  float s = 1.f/(1.f + __expf(isg ? -2.f*x : -x));
  return isg ? (2.f*s - 1.f) : s;
}
static __device__ __forceinline__ float b2f(unsigned short u){
  union { unsigned int i; float f; } x; x.i = ((unsigned int)u)<<16; return x.f;
}
static __device__ __forceinline__ unsigned short f2bu(float f){
  bf16 b = __float2bfloat16(f);
  return *reinterpret_cast<unsigned short*>(&b);
}
static __device__ __forceinline__ bfrag8 asfrag(intx4 v){
  union { intx4 i; bfrag8 f; } u; u.i = v; return u.f;
}

// ---- coherence-point accesses for cross-block RNN state (HIP atomics) ----
static __device__ __forceinline__ bfrag8 ldfrag_coh(const bf16* p){
  unsigned long long u0 = __hip_atomic_load((const unsigned long long*)p,     __ATOMIC_RELAXED, __HIP_MEMORY_SCOPE_SYSTEM);
  unsigned long long u1 = __hip_atomic_load((const unsigned long long*)p + 1, __ATOMIC_RELAXED, __HIP_MEMORY_SCOPE_SYSTEM);
  union { unsigned long long u[2]; bfrag8 f; } x; x.u[0]=u0; x.u[1]=u1;
  return x.f;
}
static __device__ __forceinline__ void stpair_coh(bf16* p, float lo, float hi){
  unsigned int pk = (unsigned int)f2bu(lo) | ((unsigned int)f2bu(hi) << 16);
  __hip_atomic_store((unsigned int*)p, pk, __ATOMIC_RELAXED, __HIP_MEMORY_SCOPE_SYSTEM);
}
static __device__ __forceinline__ void pollge(unsigned int* p, unsigned int tgt){
  while (__hip_atomic_load(p, __ATOMIC_RELAXED, __HIP_MEMORY_SCOPE_AGENT) < tgt)
    __builtin_amdgcn_s_sleep(2);
}

// ---------------------------------------------------------------------------
// prep: build padded bf16 X = [sentinel ; concat(input, tag)]  -> [32768][512]
// ---------------------------------------------------------------------------
__global__ __launch_bounds__(256) void prep_x(const float* __restrict__ input,
    const float* __restrict__ tag, const float* __restrict__ sent,
    bf16* __restrict__ Xb)
{
  const size_t stp = (size_t)gridDim.x * blockDim.x;
  for (size_t i = (size_t)blockIdx.x*blockDim.x + threadIdx.x; i < (size_t)NSEQ*KXP; i += stp){
    int m = (int)(i >> 9), k = (int)(i & 511);
    int b = m >> 9, s = m & 511;
    float v;
    if (k >= DD)        v = 0.f;
    else if (s == 0)    v = sent[k];
    else if (k < 400)   v = input[(size_t)(b*TT + s-1)*400 + k];
    else                v = tag  [(size_t)(b*TT + s-1)*100 + (k-400)];
    Xb[i] = __float2bfloat16(v);
  }
}

// ---------------------------------------------------------------------------
// prep: weight conversions with gate interleave n=4j+g, bias folds
// ---------------------------------------------------------------------------
__global__ __launch_bounds__(256) void prep_w(
  const float* __restrict__ gWih0, const float* __restrict__ gWhh0,
  const float* __restrict__ gbih0, const float* __restrict__ gbhh0,
  const float* __restrict__ gWih1, const float* __restrict__ gWhh1,
  const float* __restrict__ gbih1, const float* __restrict__ gbhh1,
  const float* __restrict__ eWih0, const float* __restrict__ eWhh0,
  const float* __restrict__ ebih0, const float* __restrict__ ebhh0,
  const float* __restrict__ eWih1, const float* __restrict__ eWhh1,
  const float* __restrict__ ebih1, const float* __restrict__ ebhh1,
  const float* __restrict__ g2eW, const float* __restrict__ htW, const float* __restrict__ dtW,
  bf16* __restrict__ W0i, bf16* __restrict__ W0r, bf16* __restrict__ W1c,
  float* __restrict__ gb0, float* __restrict__ gb1,
  bf16* __restrict__ eW0b, bf16* __restrict__ eW1ab, bf16* __restrict__ eW1bb,
  float* __restrict__ eb0, float* __restrict__ eb1, float* __restrict__ ew0cv,
  bf16* __restrict__ g2eWb, bf16* __restrict__ htWb, bf16* __restrict__ dtWb)
{
  const int st = blockIdx.x*blockDim.x + threadIdx.x;
  const int gs = gridDim.x*blockDim.x;
  // layer-0 input weights, rows interleaved n=4j+g, K padded to 512
  for (int i=st; i<G4*KXP; i+=gs){ int n=i>>9, k=i&511; int j=n>>2, g=n&3;
      W0i[i] = __float2bfloat16(k<DD ? gWih0[(size_t)(g*HG+j)*DD+k] : 0.f); }
  // layer-0 recurrent weights interleaved [1536][384]
  for (int i=st; i<G4*HG; i+=gs){ int n=i/HG, k=i-n*HG; int j=n>>2, g=n&3;
      W0r[i] = __float2bfloat16(gWhh0[(size_t)(g*HG+j)*HG+k]); }
  // layer-1 concat [Wih1|Whh1] interleaved [1536][768]
  for (int i=st; i<G4*768; i+=gs){ int n=i/768, k=i-n*768; int j=n>>2, g=n&3;
      W1c[i] = __float2bfloat16(k<HG ? gWih1[(size_t)(g*HG+j)*HG+k]
                                     : gWhh1[(size_t)(g*HG+j)*HG+(k-HG)]); }
  for (int i=st; i<G4; i+=gs){ int j=i>>2, g=i&3; int s=g*HG+j;
      gb0[i]=gbih0[s]+gbhh0[s]; gb1[i]=gbih1[s]+gbhh1[s]; }
  // edge LSTM weights
  for (int i=st; i<E4*HE; i+=gs){ eW0b[i]=__float2bfloat16(eWhh0[i]);
      eW1ab[i]=__float2bfloat16(eWih1[i]); eW1bb[i]=__float2bfloat16(eWhh1[i]); }
  for (int i=st; i<E4; i+=gs){ eb0[i]=ebih0[i]+ebhh0[i]; eb1[i]=ebih1[i]+ebhh1[i];
      ew0cv[i]=eWih0[i]; }
  for (int i=st; i<HE*HG; i+=gs) g2eWb[i]=__float2bfloat16(g2eW[i]);
  for (int i=st; i<128*HG; i+=gs){
      htWb[i] = __float2bfloat16(i<100*HG ? htW[i] : 0.f);
      dtWb[i] = __float2bfloat16(i<100*HG ? dtW[i] : 0.f); }
}

// ---------------------------------------------------------------------------
// generic MFMA GEMM:  out[M][N] = epi( A[M][KTOT] @ Wt[N][KTOT]^T )
//   EPI 0: +bias, store bf16 (ld=Nreal)
//   EPI 3: +bias, store bf16 TRANSPOSED time-major: out[(s*64+b)*1536 + col]
//   EPI 1: *maskrow +bias, store bf16
//   EPI 2: *maskrow +bias, elu, store f32, guard col<Nreal
// ---------------------------------------------------------------------------
template<int KTOT,int BN,int WAVES_M,int WAVES_N,int EPI>
__global__ __launch_bounds__(256) void gemm_mfma(
    const bf16* __restrict__ A, const bf16* __restrict__ Wt,
    const float* __restrict__ bias, const int* __restrict__ mask,
    void* __restrict__ outp, int Nreal)
{
  constexpr int WMT = 128/(WAVES_M*16);
  constexpr int WNT = BN /(WAVES_N*16);
  __shared__ alignas(16) bf16 As[128][32];
  __shared__ alignas(16) bf16 Bs[BN][32];
  const int tid = threadIdx.x;
  const int bm = blockIdx.x & 255, bn = blockIdx.x >> 8;
  const int m0 = bm*128, n0 = bn*BN;
  const int wid = tid>>6, l = tid&63, lj = l&15, lq = l>>4;
  const int wm = wid / WAVES_N, wn = wid % WAVES_N;
  floatx4 acc[WMT][WNT] = {};
  for (int k0 = 0; k0 < KTOT; k0 += 32){
    __syncthreads();
    for (int c = tid; c < 128*4; c += 256){
      int row = c>>2, ch = c&3;
      *(uint4*)&As[row][ch*8] = *(const uint4*)&A[(size_t)(m0+row)*KTOT + k0 + ch*8];
    }
    for (int c = tid; c < BN*4; c += 256){
      int row = c>>2, ch = c&3;
      *(uint4*)&Bs[row][ch*8] = *(const uint4*)&Wt[(size_t)(n0+row)*KTOT + k0 + ch*8];
    }
    __syncthreads();
    bfrag8 af[WMT]; bfrag8 bfr[WNT];
    #pragma unroll
    for (int mi=0;mi<WMT;++mi) af[mi]  = *(const bfrag8*)&As[wm*WMT*16 + mi*16 + lj][lq*8];
    #pragma unroll
    for (int ni=0;ni<WNT;++ni) bfr[ni] = *(const bfrag8*)&Bs[wn*WNT*16 + ni*16 + lj][lq*8];
    #pragma unroll
    for (int mi=0;mi<WMT;++mi)
      #pragma unroll
      for (int ni=0;ni<WNT;++ni)
        acc[mi][ni] = MFMA16(af[mi], bfr[ni], acc[mi][ni]);
  }
  #pragma unroll
  for (int mi=0;mi<WMT;++mi){
    #pragma unroll
    for (int ni=0;ni<WNT;++ni){
      #pragma unroll
      for (int r=0;r<4;++r){
        int grow = m0 + wm*WMT*16 + mi*16 + 4*lq + r;
        int gcol = n0 + wn*WNT*16 + ni*16 + lj;
        float v = acc[mi][ni][r];
        if (EPI == 0){
          v += bias[gcol];
          ((bf16*)outp)[(size_t)grow*Nreal + gcol] = __float2bfloat16(v);
        } else if (EPI == 3){
          v += bias[gcol];
          int s = grow & 511, b = grow >> 9;
          ((bf16*)outp)[((size_t)s*BB + b)*G4 + gcol] = __float2bfloat16(v);
        } else {
          int s = grow & 511, b = grow >> 9;
          float mk = (s==0) ? 1.f : (float)mask[b*TT + s - 1];
          v = v*mk + bias[gcol];
          if (EPI == 1){
            ((bf16*)outp)[(size_t)grow*Nreal + gcol] = __float2bfloat16(v);
          } else {
            v = v > 0.f ? v : expm1f(v);
            if (gcol < Nreal) ((float*)outp)[(size_t)grow*Nreal + gcol] = v;
          }
        }
      }
    }
  }
}

// ---------------------------------------------------------------------------
// persistent graph-LSTM recurrence — R3-proven structure (96 blocks x 256 thr,
// decoupled counters, __syncthreads-fenced waits) + two local perf changes:
//   (1) weight fragments pinned in VGPRs via empty asm (stops per-round remat)
//   (2) coherent h-loads hoisted into ha[] below the barrier, ahead of MFMAs
// blocks 0..47 layer0 (round it computes t=it, rounds 0..511)
// blocks 48..95 layer1 (round it computes t=it-1, rounds 1..512)
// ctr lines: ctrs[(0..3)*64] = L0 arrivals (12 blocks/line), [(4..7)*64] = L1.
// Waits at round it: L0: L0 lines >= 12*it; L1 lines >= 12*(it-2) (it>=3).
//                    L1: L0 lines >= 12*it; L1 lines >= 12*it (it>=2).
// ---------------------------------------------------------------------------
template<int IS1>
__device__ __forceinline__ void rnn_body(int bid, int tid,
    const bf16* __restrict__ G0t, const bf16* __restrict__ Wsrc,
    const float* __restrict__ gb1,
    bf16* __restrict__ h0r, bf16* __restrict__ h1seq, unsigned int* __restrict__ ctrs)
{
  constexpr int KW = IS1 ? 768 : 384;
  constexpr int KF = IS1 ? 24 : 12;
  const int bl = IS1 ? bid-48 : bid;
  const int w = tid>>6, l = tid&63, lj = l&15, lq = l>>4;
  const int m0 = w*16;          // wave = batch tile
  const int n0 = bl*32;         // block's 2 N-tiles: gate cols [n0, n0+32)
  const int a  = lj>>2;         // hidden index within 4-wide quad group
  const int gl = l&3;           // gate owned by this lane (i,f,g,o)
  const bool isg = (gl==2);

  // recurrent weights in registers, pinned (no rematerialization)
  intx4 Wr0[KF], Wr1[KF];
  #pragma unroll
  for (int kf=0; kf<KF; ++kf){
    Wr0[kf] = *(const intx4*)&Wsrc[(size_t)(n0 + lj)*KW      + kf*32 + lq*8];
    Wr1[kf] = *(const intx4*)&Wsrc[(size_t)(n0 + 16 + lj)*KW + kf*32 + lq*8];
  }
  #pragma unroll
  for (int kf=0; kf<KF; ++kf)
    asm volatile("" : "+v"(Wr0[kf]), "+v"(Wr1[kf]));

  float bi0 = 0.f, bi1 = 0.f;
  if (IS1){ bi0 = gb1[n0 + 4*a + gl]; bi1 = gb1[n0 + 16 + 4*a + gl]; }

  float c0s[4]={0,0,0,0}, c1s[4]={0,0,0,0};
  unsigned short g0pre[2][4];
  if (!IS1){
    #pragma unroll
    for (int nt=0;nt<2;++nt)
      #pragma unroll
      for (int r=0;r<4;++r)
        g0pre[nt][r] = *(const unsigned short*)&G0t[(size_t)(m0 + 4*lq + r)*G4 + n0 + nt*16 + 4*a + gl];
  }
  const int ITMAX = IS1 ? SS : (SS-1);
  for (int it=0; it<=ITMAX; ++it){
    // ---- wait phase (R3-exact; __syncthreads is the acquire fence) ----
    if (it > 0){
      if (tid < 4){
        pollge(&ctrs[tid*64], 12u*(unsigned)it);
      } else if (tid < 8){
        if (IS1){ if (it >= 2) pollge(&ctrs[tid*64], 12u*(unsigned)it); }
        else    { if (it >= 3) pollge(&ctrs[tid*64], 12u*(unsigned)(it-2)); }
      }
      __syncthreads();
    }
    // ---- compute phase ----
    if (!IS1 || it >= 1){
      const int t = IS1 ? it-1 : it;
      // batched coherent h loads (below the barrier -> no hoist hazard)
      bfrag8 ha[KF];
      if (IS1){
        const bf16* hb0 = h0r + (size_t)((it-1)&3)*(BB*HG) + (size_t)(m0+lj)*HG;
        #pragma unroll
        for (int kf=0;kf<12;++kf) ha[kf] = ldfrag_coh(hb0 + kf*32 + lq*8);
        if (t > 0){
          const bf16* hb1 = h1seq + ((size_t)(m0+lj)*SS + (t-1))*HG;
          #pragma unroll
          for (int kf=12;kf<24;++kf) ha[kf] = ldfrag_coh(hb1 + (kf-12)*32 + lq*8);
        }
      } else if (t > 0){
        const bf16* hb = h0r + (size_t)((t-1)&3)*(BB*HG) + (size_t)(m0+lj)*HG;
        #pragma unroll
        for (int kf=0;kf<12;++kf) ha[kf] = ldfrag_coh(hb + kf*32 + lq*8);
      }
      floatx4 aA0={0,0,0,0}, aB0={0,0,0,0}, aA1={0,0,0,0}, aB1={0,0,0,0};
      if (IS1 || t > 0){
        #pragma unroll
        for (int kf=0;kf<12;++kf){
          if (kf&1){ aB0 = MFMA16(ha[kf], asfrag(Wr0[kf]), aB0); aB1 = MFMA16(ha[kf], asfrag(Wr1[kf]), aB1); }
          else     { aA0 = MFMA16(ha[kf], asfrag(Wr0[kf]), aA0); aA1 = MFMA16(ha[kf], asfrag(Wr1[kf]), aA1); }
        }
      }
      if (IS1 && t > 0){
        #pragma unroll
        for (int kf=12;kf<24;++kf){
          if (kf&1){ aB0 = MFMA16(ha[kf], asfrag(Wr0[kf]), aB0); aB1 = MFMA16(ha[kf], asfrag(Wr1[kf]), aB1); }
          else     { aA0 = MFMA16(ha[kf], asfrag(Wr0[kf]), aA0); aA1 = MFMA16(ha[kf], asfrag(Wr1[kf]), aA1); }
        }
      }
      const floatx4 s0 = aA0 + aB0, s1 = aA1 + aB1;
      #pragma unroll
      for (int nt=0; nt<2; ++nt){
        #pragma unroll
        for (int r=0; r<4; ++r){
          float x = nt ? s1[r] : s0[r];
          x += IS1 ? (nt ? bi1 : bi0) : b2f(g0pre[nt][r]);
          float av = actv(x, isg);            // own gate only
          float i_ = __shfl(av, (l&60)|0);
          float f_ = __shfl(av, (l&60)|1);
          float g_ = __shfl(av, (l&60)|2);
          float o_ = __shfl(av, (l&60)|3);
          float cp = nt ? c1s[r] : c0s[r];
          float c = f_*cp + i_*g_;
          if (nt) c1s[r] = c; else c0s[r] = c;
          float h = o_*tanh_(c);
          float hn = __shfl(h, l^4);          // neighbor quad's h (a+1)
          if ((l&7) == 0){
            int bb = m0 + 4*lq + r;
            int jh = bl*8 + nt*4 + a;         // a even here
            bf16* hp = IS1 ? (h1seq + ((size_t)bb*SS + t)*HG + jh)
                           : (h0r + (size_t)(it&3)*(BB*HG) + (size_t)bb*HG + jh);
            stpair_coh(hp, h, hn);
          }
        }
      }
      // prefetch next step's G0 pre-acts (read-only, plain loads)
      if (!IS1 && it+1 < SS){
        #pragma unroll
        for (int nt=0;nt<2;++nt)
          #pragma unroll
          for (int r=0;r<4;++r)
            g0pre[nt][r] = *(const unsigned short*)&G0t[((size_t)(it+1)*BB + m0 + 4*lq + r)*G4 + n0 + nt*16 + 4*a + gl];
      }
    }
    // ---- signal phase ----
    asm volatile("s_waitcnt vmcnt(0) lgkmcnt(0)" ::: "memory");
    __syncthreads();
    if (tid == 0)
      __hip_atomic_fetch_add(&ctrs[((IS1?4:0) + (bl&3))*64], 1u,
                             __ATOMIC_RELAXED, __HIP_MEMORY_SCOPE_AGENT);
  }
}

__global__ __launch_bounds__(256,1) void graph_rnn(
    const bf16* __restrict__ G0t, const bf16* __restrict__ W0r, const bf16* __restrict__ W1c,
    const float* __restrict__ gb1, bf16* __restrict__ h0r, bf16* __restrict__ h1seq,
    unsigned int* ctrs)
{
  if (blockIdx.x < 48) rnn_body<0>(blockIdx.x, threadIdx.x, G0t, W0r, gb1, h0r, h1seq, ctrs);
  else                 rnn_body<1>(blockIdx.x, threadIdx.x, G0t, W1c, gb1, h0r, h1seq, ctrs);
}

// ---------------------------------------------------------------------------
// fused 2-layer edge LSTM, 33 steps, + cls dot, banded arc writeback.
// ---------------------------------------------------------------------------
__global__ __launch_bounds__(256) void edge_lstm(
    const bf16* __restrict__ projb,
    const bf16* __restrict__ eW0b, const bf16* __restrict__ eW1ab, const bf16* __restrict__ eW1bb,
    const float* __restrict__ eb0, const float* __restrict__ eb1, const float* __restrict__ ew0c,
    const float* __restrict__ clsW, const float* __restrict__ clsb_p, const float* __restrict__ bos_p,
    const int* __restrict__ heads, float* __restrict__ arc)
{
  __shared__ alignas(16) bf16 hbuf0[16][72];
  __shared__ alignas(16) bf16 hbuf1[16][72];
  __shared__ float lbuf[4][16];
  const int tid = threadIdx.x, w = tid>>6, l = tid&63, lj = l&15, lq = l>>4;
  const int seq0 = blockIdx.x * 16;
  const int jglob = w*16 + lj;
  for (int i = tid; i < 16*64; i += 256){
    int sl = i >> 6, jj = i & 63;
    bf16 v = projb[(size_t)(seq0+sl)*HE + jj];
    hbuf0[sl][jj] = v; hbuf1[sl][jj] = v;
  }
  bfrag8 W0f[4][2], W1af[4][2], W1bf[4][2];
  #pragma unroll
  for (int g=0; g<4; ++g){
    #pragma unroll
    for (int kk=0; kk<2; ++kk){
      size_t offw = (size_t)(g*HE + jglob)*HE + kk*32 + lq*8;
      W0f [g][kk] = *(const bfrag8*)&eW0b [offw];
      W1af[g][kk] = *(const bfrag8*)&eW1ab[offw];
      W1bf[g][kk] = *(const bfrag8*)&eW1bb[offw];
    }
  }
  float ebr0[4], ebr1[4], ewr[4];
  #pragma unroll
  for (int g=0; g<4; ++g){ ebr0[g]=eb0[g*HE+jglob]; ebr1[g]=eb1[g*HE+jglob]; ewr[g]=ew0c[g*HE+jglob]; }
  const float clswj = clsW[jglob];
  const float bos = bos_p[0], clsb = clsb_p[0];
  int hd[4]; float c0r[4]={0,0,0,0}, c1r[4]={0,0,0,0};
  #pragma unroll
  for (int r=0;r<4;++r){
    int sq = seq0 + 4*lq + r;
    int b = sq >> 9, s = sq & 511;
    hd[r] = (s==0) ? 0 : heads[b*TT + s - 1];
  }
  __syncthreads();
  for (int j=0; j<33; ++j){
    floatx4 acc0[4] = {};
    bfrag8 a0[2];
    #pragma unroll
    for (int kk=0; kk<2; ++kk)
      a0[kk] = *(const bfrag8*)((const char*)&hbuf0[0][0] + lj*144 + kk*64 + lq*16);
    #pragma unroll
    for (int g=0; g<4; ++g)
      #pragma unroll
      for (int kk=0; kk<2; ++kk)
        acc0[g] = MFMA16(a0[kk], W0f[g][kk], acc0[g]);
    __syncthreads();
    float h0v[4];
    #pragma unroll
    for (int r=0;r<4;++r){
      float x = (j==0) ? bos : ((hd[r] == j-1) ? 1.f : 0.f);
      float pi = acc0[0][r] + ebr0[0] + x*ewr[0];
      float pf = acc0[1][r] + ebr0[1] + x*ewr[1];
      float pg = acc0[2][r] + ebr0[2] + x*ewr[2];
      float po = acc0[3][r] + ebr0[3] + x*ewr[3];
      float i_=sigm_(pi), f_=sigm_(pf), g_=tanh_(pg), o_=sigm_(po);
      c0r[r] = f_*c0r[r] + i_*g_;
      h0v[r] = o_*tanh_(c0r[r]);
    }
    #pragma unroll
    for (int r=0;r<4;++r) hbuf0[4*lq + r][jglob] = __float2bfloat16(h0v[r]);
    __syncthreads();
    floatx4 acc1[4] = {};
    bfrag8 a1[2], a2[2];
    #pragma unroll
    for (int kk=0;kk<2;++kk){
      a1[kk] = *(const bfrag8*)((const char*)&hbuf0[0][0] + lj*144 + kk*64 + lq*16);
      a2[kk] = *(const bfrag8*)((const char*)&hbuf1[0][0] + lj*144 + kk*64 + lq*16);
    }
    #pragma unroll
    for (int g=0; g<4; ++g){
      #pragma unroll
      for (int kk=0;kk<2;++kk){
        acc1[g] = MFMA16(a1[kk], W1af[g][kk], acc1[g]);
        acc1[g] = MFMA16(a2[kk], W1bf[g][kk], acc1[g]);
      }
    }
    __syncthreads();
    float p[4];
    #pragma unroll
    for (int r=0;r<4;++r){
      float pi = acc1[0][r] + ebr1[0];
      float pf = acc1[1][r] + ebr1[1];
      float pg = acc1[2][r] + ebr1[2];
      float po = acc1[3][r] + ebr1[3];
      float i_=sigm_(pi), f_=sigm_(pf), g_=tanh_(pg), o_=sigm_(po);
      c1r[r] = f_*c1r[r] + i_*g_;
      float h1 = o_*tanh_(c1r[r]);
      hbuf1[4*lq + r][jglob] = __float2bfloat16(h1);
      p[r] = h1 * clswj;
    }
    #pragma unroll
    for (int mk=1; mk<16; mk<<=1)
      #pragma unroll
      for (int r=0;r<4;++r) p[r] += __shfl_xor(p[r], mk, 64);
    if (lj == 0){
      #pragma unroll
      for (int r=0;r<4;++r) lbuf[w][4*lq + r] = p[r];
    }
    __syncthreads();
    if (tid < 16 && j >= 1){
      int sq = seq0 + tid;
      float v = lbuf[0][tid] + lbuf[1][tid] + lbuf[2][tid] + lbuf[3][tid] + clsb;
      arc[(size_t)sq*SS + (j-1)] = v;
    }
  }
}

// ---------------------------------------------------------------------------
extern "C" void kernel_launch(void* const* d_in, const int* in_sizes, int n_in,
                              void* d_out, int out_size, void* d_ws, size_t ws_size,
                              hipStream_t stream)
{
  const float* input = (const float*)d_in[0];
  const float* tag   = (const float*)d_in[1];
  const int*   mask  = (const int*)  d_in[2];
  const int*   heads = (const int*)  d_in[3];
  const float* sent  = (const float*)d_in[4];
  const float* bosp  = (const float*)d_in[5];
  const float* gWih0 = (const float*)d_in[6];
  const float* gWhh0 = (const float*)d_in[7];
  const float* gbih0 = (const float*)d_in[8];
  const float* gbhh0 = (const float*)d_in[9];
  const float* gWih1 = (const float*)d_in[10];
  const float* gWhh1 = (const float*)d_in[11];
  const float* gbih1 = (const float*)d_in[12];
  const float* gbhh1 = (const float*)d_in[13];
  const float* eWih0 = (const float*)d_in[14];
  const float* eWhh0 = (const float*)d_in[15];
  const float* ebih0 = (const float*)d_in[16];
  const float* ebhh0 = (const float*)d_in[17];
  const float* eWih1 = (const float*)d_in[18];
  const float* eWhh1 = (const float*)d_in[19];
  const float* ebih1 = (const float*)d_in[20];
  const float* ebhh1 = (const float*)d_in[21];
  const float* g2eW  = (const float*)d_in[22];
  const float* g2eb  = (const float*)d_in[23];
  const float* clsW  = (const float*)d_in[24];
  const float* clsb  = (const float*)d_in[25];
  const float* htW   = (const float*)d_in[26];
  const float* htb   = (const float*)d_in[27];
  const float* dtW   = (const float*)d_in[28];
  const float* dtb   = (const float*)d_in[29];

  char* wsb = (char*)d_ws;
  size_t off = 0;
  auto take = [&](size_t bytes)->char* {
    char* p = wsb + off;
    off = (off + bytes + 255) & ~(size_t)255;
    return p;
  };
  bf16*  Xb     = (bf16*) take((size_t)NSEQ*KXP*2);   // 33.6 MB
  bf16*  W0i    = (bf16*) take((size_t)G4*KXP*2);     // interleaved Wih0
  bf16*  W0r    = (bf16*) take((size_t)G4*HG*2);      // interleaved Whh0
  bf16*  W1c    = (bf16*) take((size_t)G4*768*2);     // interleaved [Wih1|Whh1]
  float* gb0i   = (float*)take(G4*4);
  float* gb1i   = (float*)take(G4*4);
  bf16*  G0t    = (bf16*) take((size_t)NSEQ*G4*2);    // 100.7 MB, time-major [t][b][1536]
  bf16*  h0ring = (bf16*) take((size_t)4*BB*HG*2);    // 4-slot h0 exchange ring
  bf16*  h1seq  = (bf16*) take((size_t)NSEQ*HG*2);    // 25.2 MB  [b][t][384]
  unsigned int* ctrs = (unsigned int*)take(8*64*4);   // 8 counter lines x 256B
  bf16*  projb  = (bf16*) take((size_t)NSEQ*HE*2);
  bf16*  eW0b   = (bf16*) take(E4*HE*2);
  bf16*  eW1ab  = (bf16*) take(E4*HE*2);
  bf16*  eW1bb  = (bf16*) take(E4*HE*2);
  float* eb0w   = (float*)take(E4*4);
  float* eb1w   = (float*)take(E4*4);
  float* ew0cw  = (float*)take(E4*4);
  bf16*  g2eWb  = (bf16*) take(HE*HG*2);
  bf16*  htWb   = (bf16*) take(128*HG*2);
  bf16*  dtWb   = (bf16*) take(128*HG*2);

  (void)hipMemsetAsync(d_out, 0, (size_t)16777216*4, stream);
  (void)hipMemsetAsync(ctrs, 0, 8*64*4, stream);

  prep_x<<<2048,256,0,stream>>>(input, tag, sent, Xb);
  prep_w<<<512,256,0,stream>>>(gWih0,gWhh0,gbih0,gbhh0,gWih1,gWhh1,gbih1,gbhh1,
                               eWih0,eWhh0,ebih0,ebhh0,eWih1,eWhh1,ebih1,ebhh1,
                               g2eW,htW,dtW,
                               W0i,W0r,W1c,gb0i,gb1i,eW0b,eW1ab,eW1bb,
                               eb0w,eb1w,ew0cw,g2eWb,htWb,dtWb);

  // layer-0 input gates, time-major: G0t[t][b][:] = X@W0i^T + gb0
  gemm_mfma<KXP,128,2,2,3><<<3072,256,0,stream>>>(Xb, W0i, gb0i, nullptr, (void*)G0t, G4);

  // persistent 2-layer recurrence (R3 structure + pinned weights + batched loads)
  graph_rnn<<<96,256,0,stream>>>(G0t, W0r, W1c, gb1i, h0ring, h1seq, ctrs);

  // proj = mask * (graph_state @ g2e_W^T) + g2e_b   -> bf16
  gemm_mfma<HG,64,4,1,1><<<256,256,0,stream>>>(h1seq, g2eWb, g2eb, mask, (void*)projb, HE);

  // banded teacher-forced edge LSTM + cls + arc writeback
  edge_lstm<<<2048,256,0,stream>>>(projb, eW0b, eW1ab, eW1bb, eb0w, eb1w, ew0cw,
                                   clsW, clsb, bosp, heads, (float*)d_out);

  // tag feedforwards: elu(mask*(graph_state @ W^T) + b)
  gemm_mfma<HG,128,2,2,2><<<256,256,0,stream>>>(h1seq, htWb, htb, mask,
      (void*)((float*)d_out + 16777216), 100);
  gemm_mfma<HG,128,2,2,2><<<256,256,0,stream>>>(h1seq, dtWb, dtb, mask,
      (void*)((float*)d_out + 16777216 + 3276800), 100);
}

// Round 7
// 4933.699 us; speedup vs baseline: 1.0804x; 1.0804x over previous
//
#include <hip/hip_runtime.h>
#include <hip/hip_bf16.h>
#include <stdint.h>

// ---------------- problem dims ----------------
#define BB   64
#define TT   511
#define SS   512
#define DD   500
#define KXP  512          // padded input dim for layer-0 input GEMM
#define HG   384
#define G4   1536
#define HE   64
#define E4   256
#define NSEQ (BB*SS)      // 32768

typedef __hip_bfloat16 bf16;
typedef float  floatx4 __attribute__((ext_vector_type(4)));
typedef int    intx4   __attribute__((ext_vector_type(4)));
typedef __bf16 bfrag8  __attribute__((ext_vector_type(8)));

// v_mfma_f32_16x16x32_bf16 fragment layout (gfx950):
//   A: lane l holds A[l&15][8*(l>>4)+i]      (16B contiguous along K, A stored [M][K])
//   B: lane l holds W[n=l&15][8*(l>>4)+i]    (weights stored [N][K] = torch [out][in])
//   D: lane l, reg r holds D[4*(l>>4)+r][l&15]
static __device__ __forceinline__ floatx4 MFMA16(bfrag8 a, bfrag8 b, floatx4 c){
  return __builtin_amdgcn_mfma_f32_16x16x32_bf16(a, b, c, 0, 0, 0);
}
static __device__ __forceinline__ float sigm_(float x){ return 1.f/(1.f + __expf(-x)); }
static __device__ __forceinline__ float tanh_(float x){
  x = fminf(fmaxf(x, -15.f), 15.f);
  float e = __expf(2.f*x);
  return (e - 1.f)/(e + 1.f);
}
// per-lane gate activation: sigm for i,f,o; tanh via 2*sigm(2x)-1 for g
static __device__ __forceinline__ float actv(float x, bool isg){
  float s = 1.f/(1.f + __expf(isg ? -2.f*x : -x));
  return isg ? (2.f*s - 1.f) : s;
}
static __device__ __forceinline__ float b2f(unsigned short u){
  union { unsigned int i; float f; } x; x.i = ((unsigned int)u)<<16; return x.f;
}
static __device__ __forceinline__ unsigned short f2bu(float f){
  bf16 b = __float2bfloat16(f);
  return *reinterpret_cast<unsigned short*>(&b);
}
static __device__ __forceinline__ bfrag8 asfrag(intx4 v){
  union { intx4 i; bfrag8 f; } u; u.i = v; return u.f;
}

// ---- coherence-point accesses for cross-block RNN state (HIP atomics) ----
static __device__ __forceinline__ bfrag8 ldfrag_coh(const bf16* p){
  unsigned long long u0 = __hip_atomic_load((const unsigned long long*)p,     __ATOMIC_RELAXED, __HIP_MEMORY_SCOPE_SYSTEM);
  unsigned long long u1 = __hip_atomic_load((const unsigned long long*)p + 1, __ATOMIC_RELAXED, __HIP_MEMORY_SCOPE_SYSTEM);
  union { unsigned long long u[2]; bfrag8 f; } x; x.u[0]=u0; x.u[1]=u1;
  return x.f;
}
static __device__ __forceinline__ void stpair_coh(bf16* p, float lo, float hi){
  unsigned int pk = (unsigned int)f2bu(lo) | ((unsigned int)f2bu(hi) << 16);
  __hip_atomic_store((unsigned int*)p, pk, __ATOMIC_RELAXED, __HIP_MEMORY_SCOPE_SYSTEM);
}
static __device__ __forceinline__ void pollge(unsigned int* p, unsigned int tgt){
  while (__hip_atomic_load(p, __ATOMIC_RELAXED, __HIP_MEMORY_SCOPE_AGENT) < tgt)
    __builtin_amdgcn_s_sleep(4);
}

// ---------------------------------------------------------------------------
// prep: build padded bf16 X = [sentinel ; concat(input, tag)]  -> [32768][512]
// ---------------------------------------------------------------------------
__global__ __launch_bounds__(256) void prep_x(const float* __restrict__ input,
    const float* __restrict__ tag, const float* __restrict__ sent,
    bf16* __restrict__ Xb)
{
  const size_t stp = (size_t)gridDim.x * blockDim.x;
  for (size_t i = (size_t)blockIdx.x*blockDim.x + threadIdx.x; i < (size_t)NSEQ*KXP; i += stp){
    int m = (int)(i >> 9), k = (int)(i & 511);
    int b = m >> 9, s = m & 511;
    float v;
    if (k >= DD)        v = 0.f;
    else if (s == 0)    v = sent[k];
    else if (k < 400)   v = input[(size_t)(b*TT + s-1)*400 + k];
    else                v = tag  [(size_t)(b*TT + s-1)*100 + (k-400)];
    Xb[i] = __float2bfloat16(v);
  }
}

// ---------------------------------------------------------------------------
// prep: weight conversions with gate interleave n=4j+g, bias folds
// ---------------------------------------------------------------------------
__global__ __launch_bounds__(256) void prep_w(
  const float* __restrict__ gWih0, const float* __restrict__ gWhh0,
  const float* __restrict__ gbih0, const float* __restrict__ gbhh0,
  const float* __restrict__ gWih1, const float* __restrict__ gWhh1,
  const float* __restrict__ gbih1, const float* __restrict__ gbhh1,
  const float* __restrict__ eWih0, const float* __restrict__ eWhh0,
  const float* __restrict__ ebih0, const float* __restrict__ ebhh0,
  const float* __restrict__ eWih1, const float* __restrict__ eWhh1,
  const float* __restrict__ ebih1, const float* __restrict__ ebhh1,
  const float* __restrict__ g2eW, const float* __restrict__ htW, const float* __restrict__ dtW,
  bf16* __restrict__ W0i, bf16* __restrict__ W0r, bf16* __restrict__ W1c,
  float* __restrict__ gb0, float* __restrict__ gb1,
  bf16* __restrict__ eW0b, bf16* __restrict__ eW1ab, bf16* __restrict__ eW1bb,
  float* __restrict__ eb0, float* __restrict__ eb1, float* __restrict__ ew0cv,
  bf16* __restrict__ g2eWb, bf16* __restrict__ htWb, bf16* __restrict__ dtWb)
{
  const int st = blockIdx.x*blockDim.x + threadIdx.x;
  const int gs = gridDim.x*blockDim.x;
  // layer-0 input weights, rows interleaved n=4j+g, K padded to 512
  for (int i=st; i<G4*KXP; i+=gs){ int n=i>>9, k=i&511; int j=n>>2, g=n&3;
      W0i[i] = __float2bfloat16(k<DD ? gWih0[(size_t)(g*HG+j)*DD+k] : 0.f); }
  // layer-0 recurrent weights interleaved [1536][384]
  for (int i=st; i<G4*HG; i+=gs){ int n=i/HG, k=i-n*HG; int j=n>>2, g=n&3;
      W0r[i] = __float2bfloat16(gWhh0[(size_t)(g*HG+j)*HG+k]); }
  // layer-1 concat [Wih1|Whh1] interleaved [1536][768]
  for (int i=st; i<G4*768; i+=gs){ int n=i/768, k=i-n*768; int j=n>>2, g=n&3;
      W1c[i] = __float2bfloat16(k<HG ? gWih1[(size_t)(g*HG+j)*HG+k]
                                     : gWhh1[(size_t)(g*HG+j)*HG+(k-HG)]); }
  for (int i=st; i<G4; i+=gs){ int j=i>>2, g=i&3; int s=g*HG+j;
      gb0[i]=gbih0[s]+gbhh0[s]; gb1[i]=gbih1[s]+gbhh1[s]; }
  // edge LSTM weights
  for (int i=st; i<E4*HE; i+=gs){ eW0b[i]=__float2bfloat16(eWhh0[i]);
      eW1ab[i]=__float2bfloat16(eWih1[i]); eW1bb[i]=__float2bfloat16(eWhh1[i]); }
  for (int i=st; i<E4; i+=gs){ eb0[i]=ebih0[i]+ebhh0[i]; eb1[i]=ebih1[i]+ebhh1[i];
      ew0cv[i]=eWih0[i]; }
  for (int i=st; i<HE*HG; i+=gs) g2eWb[i]=__float2bfloat16(g2eW[i]);
  for (int i=st; i<128*HG; i+=gs){
      htWb[i] = __float2bfloat16(i<100*HG ? htW[i] : 0.f);
      dtWb[i] = __float2bfloat16(i<100*HG ? dtW[i] : 0.f); }
}

// ---------------------------------------------------------------------------
// generic MFMA GEMM:  out[M][N] = epi( A[M][KTOT] @ Wt[N][KTOT]^T )
//   EPI 0: +bias, store bf16 (ld=Nreal)
//   EPI 3: +bias, store bf16 TRANSPOSED time-major: out[(s*64+b)*1536 + col]
//   EPI 1: *maskrow +bias, store bf16
//   EPI 2: *maskrow +bias, elu, store f32, guard col<Nreal
// ---------------------------------------------------------------------------
template<int KTOT,int BN,int WAVES_M,int WAVES_N,int EPI>
__global__ __launch_bounds__(256) void gemm_mfma(
    const bf16* __restrict__ A, const bf16* __restrict__ Wt,
    const float* __restrict__ bias, const int* __restrict__ mask,
    void* __restrict__ outp, int Nreal)
{
  constexpr int WMT = 128/(WAVES_M*16);
  constexpr int WNT = BN /(WAVES_N*16);
  __shared__ alignas(16) bf16 As[128][32];
  __shared__ alignas(16) bf16 Bs[BN][32];
  const int tid = threadIdx.x;
  const int bm = blockIdx.x & 255, bn = blockIdx.x >> 8;
  const int m0 = bm*128, n0 = bn*BN;
  const int wid = tid>>6, l = tid&63, lj = l&15, lq = l>>4;
  const int wm = wid / WAVES_N, wn = wid % WAVES_N;
  floatx4 acc[WMT][WNT] = {};
  for (int k0 = 0; k0 < KTOT; k0 += 32){
    __syncthreads();
    for (int c = tid; c < 128*4; c += 256){
      int row = c>>2, ch = c&3;
      *(uint4*)&As[row][ch*8] = *(const uint4*)&A[(size_t)(m0+row)*KTOT + k0 + ch*8];
    }
    for (int c = tid; c < BN*4; c += 256){
      int row = c>>2, ch = c&3;
      *(uint4*)&Bs[row][ch*8] = *(const uint4*)&Wt[(size_t)(n0+row)*KTOT + k0 + ch*8];
    }
    __syncthreads();
    bfrag8 af[WMT]; bfrag8 bfr[WNT];
    #pragma unroll
    for (int mi=0;mi<WMT;++mi) af[mi]  = *(const bfrag8*)&As[wm*WMT*16 + mi*16 + lj][lq*8];
    #pragma unroll
    for (int ni=0;ni<WNT;++ni) bfr[ni] = *(const bfrag8*)&Bs[wn*WNT*16 + ni*16 + lj][lq*8];
    #pragma unroll
    for (int mi=0;mi<WMT;++mi)
      #pragma unroll
      for (int ni=0;ni<WNT;++ni)
        acc[mi][ni] = MFMA16(af[mi], bfr[ni], acc[mi][ni]);
  }
  #pragma unroll
  for (int mi=0;mi<WMT;++mi){
    #pragma unroll
    for (int ni=0;ni<WNT;++ni){
      #pragma unroll
      for (int r=0;r<4;++r){
        int grow = m0 + wm*WMT*16 + mi*16 + 4*lq + r;
        int gcol = n0 + wn*WNT*16 + ni*16 + lj;
        float v = acc[mi][ni][r];
        if (EPI == 0){
          v += bias[gcol];
          ((bf16*)outp)[(size_t)grow*Nreal + gcol] = __float2bfloat16(v);
        } else if (EPI == 3){
          v += bias[gcol];
          int s = grow & 511, b = grow >> 9;
          ((bf16*)outp)[((size_t)s*BB + b)*G4 + gcol] = __float2bfloat16(v);
        } else {
          int s = grow & 511, b = grow >> 9;
          float mk = (s==0) ? 1.f : (float)mask[b*TT + s - 1];
          v = v*mk + bias[gcol];
          if (EPI == 1){
            ((bf16*)outp)[(size_t)grow*Nreal + gcol] = __float2bfloat16(v);
          } else {
            v = v > 0.f ? v : expm1f(v);
            if (gcol < Nreal) ((float*)outp)[(size_t)grow*Nreal + gcol] = v;
          }
        }
      }
    }
  }
}

// ---------------------------------------------------------------------------
// persistent graph-LSTM recurrence — R6 structure with per-block single-writer
// flags instead of shared RMW counters.
// blocks 0..47 layer0 (round it computes t=it, rounds 0..511)
// blocks 48..95 layer1 (round it computes t=it-1, rounds 1..512)
// flags[bid] (one 64B line each) = number of completed rounds of block bid,
// written by tid0 via relaxed agent-scope STORE (single writer, no RMW).
// Waits at round it (threads 0..95 poll one flag each, then __syncthreads
// = acquire fence — prevents the R4/R5 load-hoist race):
//   L0: flags[0..47] >= it;  flags[48..95] >= it-2 (it>=3, ring backpressure)
//   L1: flags[0..47] >= it;  flags[48..95] >= it   (it>=2)
// ---------------------------------------------------------------------------
template<int IS1>
__device__ __forceinline__ void rnn_body(int bid, int tid,
    const bf16* __restrict__ G0t, const bf16* __restrict__ Wsrc,
    const float* __restrict__ gb1,
    bf16* __restrict__ h0r, bf16* __restrict__ h1seq, unsigned int* __restrict__ flags)
{
  constexpr int KW = IS1 ? 768 : 384;
  constexpr int KF = IS1 ? 24 : 12;
  const int bl = IS1 ? bid-48 : bid;
  const int w = tid>>6, l = tid&63, lj = l&15, lq = l>>4;
  const int m0 = w*16;          // wave = batch tile
  const int n0 = bl*32;         // block's 2 N-tiles: gate cols [n0, n0+32)
  const int a  = lj>>2;         // hidden index within 4-wide quad group
  const int gl = l&3;           // gate owned by this lane (i,f,g,o)
  const bool isg = (gl==2);

  // recurrent weights in registers, pinned
  intx4 Wr0[KF], Wr1[KF];
  #pragma unroll
  for (int kf=0; kf<KF; ++kf){
    Wr0[kf] = *(const intx4*)&Wsrc[(size_t)(n0 + lj)*KW      + kf*32 + lq*8];
    Wr1[kf] = *(const intx4*)&Wsrc[(size_t)(n0 + 16 + lj)*KW + kf*32 + lq*8];
  }
  #pragma unroll
  for (int kf=0; kf<KF; ++kf)
    asm volatile("" : "+v"(Wr0[kf]), "+v"(Wr1[kf]));

  float bi0 = 0.f, bi1 = 0.f;
  if (IS1){ bi0 = gb1[n0 + 4*a + gl]; bi1 = gb1[n0 + 16 + 4*a + gl]; }

  float c0s[4]={0,0,0,0}, c1s[4]={0,0,0,0};
  unsigned short g0pre[2][4];
  if (!IS1){
    #pragma unroll
    for (int nt=0;nt<2;++nt)
      #pragma unroll
      for (int r=0;r<4;++r)
        g0pre[nt][r] = *(const unsigned short*)&G0t[(size_t)(m0 + 4*lq + r)*G4 + n0 + nt*16 + 4*a + gl];
  }
  const int ITMAX = IS1 ? SS : (SS-1);
  for (int it=0; it<=ITMAX; ++it){
    // ---- wait phase: threads 0..95 poll one flag each; syncthreads = acquire ----
    if (it > 0){
      if (tid < 48){
        pollge(&flags[(size_t)tid*16], (unsigned)it);
      } else if (tid < 96){
        if (IS1){ if (it >= 2) pollge(&flags[(size_t)tid*16], (unsigned)it); }
        else    { if (it >= 3) pollge(&flags[(size_t)tid*16], (unsigned)(it-2)); }
      }
      __syncthreads();
    }
    // ---- compute phase ----
    if (!IS1 || it >= 1){
      const int t = IS1 ? it-1 : it;
      // batched coherent h loads (below the barrier -> no hoist hazard)
      bfrag8 ha[KF];
      if (IS1){
        const bf16* hb0 = h0r + (size_t)((it-1)&3)*(BB*HG) + (size_t)(m0+lj)*HG;
        #pragma unroll
        for (int kf=0;kf<12;++kf) ha[kf] = ldfrag_coh(hb0 + kf*32 + lq*8);
        if (t > 0){
          const bf16* hb1 = h1seq + ((size_t)(m0+lj)*SS + (t-1))*HG;
          #pragma unroll
          for (int kf=12;kf<24;++kf) ha[kf] = ldfrag_coh(hb1 + (kf-12)*32 + lq*8);
        }
      } else if (t > 0){
        const bf16* hb = h0r + (size_t)((t-1)&3)*(BB*HG) + (size_t)(m0+lj)*HG;
        #pragma unroll
        for (int kf=0;kf<12;++kf) ha[kf] = ldfrag_coh(hb + kf*32 + lq*8);
      }
      floatx4 aA0={0,0,0,0}, aB0={0,0,0,0}, aA1={0,0,0,0}, aB1={0,0,0,0};
      if (IS1 || t > 0){
        #pragma unroll
        for (int kf=0;kf<12;++kf){
          if (kf&1){ aB0 = MFMA16(ha[kf], asfrag(Wr0[kf]), aB0); aB1 = MFMA16(ha[kf], asfrag(Wr1[kf]), aB1); }
          else     { aA0 = MFMA16(ha[kf], asfrag(Wr0[kf]), aA0); aA1 = MFMA16(ha[kf], asfrag(Wr1[kf]), aA1); }
        }
      }
      if (IS1 && t > 0){
        #pragma unroll
        for (int kf=12;kf<24;++kf){
          if (kf&1){ aB0 = MFMA16(ha[kf], asfrag(Wr0[kf]), aB0); aB1 = MFMA16(ha[kf], asfrag(Wr1[kf]), aB1); }
          else     { aA0 = MFMA16(ha[kf], asfrag(Wr0[kf]), aA0); aA1 = MFMA16(ha[kf], asfrag(Wr1[kf]), aA1); }
        }
      }
      const floatx4 s0 = aA0 + aB0, s1 = aA1 + aB1;
      #pragma unroll
      for (int nt=0; nt<2; ++nt){
        #pragma unroll
        for (int r=0; r<4; ++r){
          float x = nt ? s1[r] : s0[r];
          x += IS1 ? (nt ? bi1 : bi0) : b2f(g0pre[nt][r]);
          float av = actv(x, isg);            // own gate only
          float i_ = __shfl(av, (l&60)|0);
          float f_ = __shfl(av, (l&60)|1);
          float g_ = __shfl(av, (l&60)|2);
          float o_ = __shfl(av, (l&60)|3);
          float cp = nt ? c1s[r] : c0s[r];
          float c = f_*cp + i_*g_;
          if (nt) c1s[r] = c; else c0s[r] = c;
          float h = o_*tanh_(c);
          float hn = __shfl(h, l^4);          // neighbor quad's h (a+1)
          if ((l&7) == 0){
            int bb = m0 + 4*lq + r;
            int jh = bl*8 + nt*4 + a;         // a even here
            bf16* hp = IS1 ? (h1seq + ((size_t)bb*SS + t)*HG + jh)
                           : (h0r + (size_t)(it&3)*(BB*HG) + (size_t)bb*HG + jh);
            stpair_coh(hp, h, hn);
          }
        }
      }
      // prefetch next step's G0 pre-acts (read-only, plain loads)
      if (!IS1 && it+1 < SS){
        #pragma unroll
        for (int nt=0;nt<2;++nt)
          #pragma unroll
          for (int r=0;r<4;++r)
            g0pre[nt][r] = *(const unsigned short*)&G0t[((size_t)(it+1)*BB + m0 + 4*lq + r)*G4 + n0 + nt*16 + 4*a + gl];
      }
    }
    // ---- signal phase: drain stores, then single-writer flag store ----
    asm volatile("s_waitcnt vmcnt(0) lgkmcnt(0)" ::: "memory");
    __syncthreads();
    if (tid == 0)
      __hip_atomic_store(&flags[(size_t)bid*16], (unsigned)(it+1),
                         __ATOMIC_RELAXED, __HIP_MEMORY_SCOPE_AGENT);
  }
}

__global__ __launch_bounds__(256,1) void graph_rnn(
    const bf16* __restrict__ G0t, const bf16* __restrict__ W0r, const bf16* __restrict__ W1c,
    const float* __restrict__ gb1, bf16* __restrict__ h0r, bf16* __restrict__ h1seq,
    unsigned int* flags)
{
  if (blockIdx.x < 48) rnn_body<0>(blockIdx.x, threadIdx.x, G0t, W0r, gb1, h0r, h1seq, flags);
  else                 rnn_body<1>(blockIdx.x, threadIdx.x, G0t, W1c, gb1, h0r, h1seq, flags);
}

// ---------------------------------------------------------------------------
// fused 2-layer edge LSTM, 33 steps, + cls dot, banded arc writeback.
// ---------------------------------------------------------------------------
__global__ __launch_bounds__(256) void edge_lstm(
    const bf16* __restrict__ projb,
    const bf16* __restrict__ eW0b, const bf16* __restrict__ eW1ab, const bf16* __restrict__ eW1bb,
    const float* __restrict__ eb0, const float* __restrict__ eb1, const float* __restrict__ ew0c,
    const float* __restrict__ clsW, const float* __restrict__ clsb_p, const float* __restrict__ bos_p,
    const int* __restrict__ heads, float* __restrict__ arc)
{
  __shared__ alignas(16) bf16 hbuf0[16][72];
  __shared__ alignas(16) bf16 hbuf1[16][72];
  __shared__ float lbuf[4][16];
  const int tid = threadIdx.x, w = tid>>6, l = tid&63, lj = l&15, lq = l>>4;
  const int seq0 = blockIdx.x * 16;
  const int jglob = w*16 + lj;
  for (int i = tid; i < 16*64; i += 256){
    int sl = i >> 6, jj = i & 63;
    bf16 v = projb[(size_t)(seq0+sl)*HE + jj];
    hbuf0[sl][jj] = v; hbuf1[sl][jj] = v;
  }
  bfrag8 W0f[4][2], W1af[4][2], W1bf[4][2];
  #pragma unroll
  for (int g=0; g<4; ++g){
    #pragma unroll
    for (int kk=0; kk<2; ++kk){
      size_t offw = (size_t)(g*HE + jglob)*HE + kk*32 + lq*8;
      W0f [g][kk] = *(const bfrag8*)&eW0b [offw];
      W1af[g][kk] = *(const bfrag8*)&eW1ab[offw];
      W1bf[g][kk] = *(const bfrag8*)&eW1bb[offw];
    }
  }
  float ebr0[4], ebr1[4], ewr[4];
  #pragma unroll
  for (int g=0; g<4; ++g){ ebr0[g]=eb0[g*HE+jglob]; ebr1[g]=eb1[g*HE+jglob]; ewr[g]=ew0c[g*HE+jglob]; }
  const float clswj = clsW[jglob];
  const float bos = bos_p[0], clsb = clsb_p[0];
  int hd[4]; float c0r[4]={0,0,0,0}, c1r[4]={0,0,0,0};
  #pragma unroll
  for (int r=0;r<4;++r){
    int sq = seq0 + 4*lq + r;
    int b = sq >> 9, s = sq & 511;
    hd[r] = (s==0) ? 0 : heads[b*TT + s - 1];
  }
  __syncthreads();
  for (int j=0; j<33; ++j){
    floatx4 acc0[4] = {};
    bfrag8 a0[2];
    #pragma unroll
    for (int kk=0; kk<2; ++kk)
      a0[kk] = *(const bfrag8*)((const char*)&hbuf0[0][0] + lj*144 + kk*64 + lq*16);
    #pragma unroll
    for (int g=0; g<4; ++g)
      #pragma unroll
      for (int kk=0; kk<2; ++kk)
        acc0[g] = MFMA16(a0[kk], W0f[g][kk], acc0[g]);
    __syncthreads();
    float h0v[4];
    #pragma unroll
    for (int r=0;r<4;++r){
      float x = (j==0) ? bos : ((hd[r] == j-1) ? 1.f : 0.f);
      float pi = acc0[0][r] + ebr0[0] + x*ewr[0];
      float pf = acc0[1][r] + ebr0[1] + x*ewr[1];
      float pg = acc0[2][r] + ebr0[2] + x*ewr[2];
      float po = acc0[3][r] + ebr0[3] + x*ewr[3];
      float i_=sigm_(pi), f_=sigm_(pf), g_=tanh_(pg), o_=sigm_(po);
      c0r[r] = f_*c0r[r] + i_*g_;
      h0v[r] = o_*tanh_(c0r[r]);
    }
    #pragma unroll
    for (int r=0;r<4;++r) hbuf0[4*lq + r][jglob] = __float2bfloat16(h0v[r]);
    __syncthreads();
    floatx4 acc1[4] = {};
    bfrag8 a1[2], a2[2];
    #pragma unroll
    for (int kk=0;kk<2;++kk){
      a1[kk] = *(const bfrag8*)((const char*)&hbuf0[0][0] + lj*144 + kk*64 + lq*16);
      a2[kk] = *(const bfrag8*)((const char*)&hbuf1[0][0] + lj*144 + kk*64 + lq*16);
    }
    #pragma unroll
    for (int g=0; g<4; ++g){
      #pragma unroll
      for (int kk=0;kk<2;++kk){
        acc1[g] = MFMA16(a1[kk], W1af[g][kk], acc1[g]);
        acc1[g] = MFMA16(a2[kk], W1bf[g][kk], acc1[g]);
      }
    }
    __syncthreads();
    float p[4];
    #pragma unroll
    for (int r=0;r<4;++r){
      float pi = acc1[0][r] + ebr1[0];
      float pf = acc1[1][r] + ebr1[1];
      float pg = acc1[2][r] + ebr1[2];
      float po = acc1[3][r] + ebr1[3];
      float i_=sigm_(pi), f_=sigm_(pf), g_=tanh_(pg), o_=sigm_(po);
      c1r[r] = f_*c1r[r] + i_*g_;
      float h1 = o_*tanh_(c1r[r]);
      hbuf1[4*lq + r][jglob] = __float2bfloat16(h1);
      p[r] = h1 * clswj;
    }
    #pragma unroll
    for (int mk=1; mk<16; mk<<=1)
      #pragma unroll
      for (int r=0;r<4;++r) p[r] += __shfl_xor(p[r], mk, 64);
    if (lj == 0){
      #pragma unroll
      for (int r=0;r<4;++r) lbuf[w][4*lq + r] = p[r];
    }
    __syncthreads();
    if (tid < 16 && j >= 1){
      int sq = seq0 + tid;
      float v = lbuf[0][tid] + lbuf[1][tid] + lbuf[2][tid] + lbuf[3][tid] + clsb;
      arc[(size_t)sq*SS + (j-1)] = v;
    }
  }
}

// ---------------------------------------------------------------------------
extern "C" void kernel_launch(void* const* d_in, const int* in_sizes, int n_in,
                              void* d_out, int out_size, void* d_ws, size_t ws_size,
                              hipStream_t stream)
{
  const float* input = (const float*)d_in[0];
  const float* tag   = (const float*)d_in[1];
  const int*   mask  = (const int*)  d_in[2];
  const int*   heads = (const int*)  d_in[3];
  const float* sent  = (const float*)d_in[4];
  const float* bosp  = (const float*)d_in[5];
  const float* gWih0 = (const float*)d_in[6];
  const float* gWhh0 = (const float*)d_in[7];
  const float* gbih0 = (const float*)d_in[8];
  const float* gbhh0 = (const float*)d_in[9];
  const float* gWih1 = (const float*)d_in[10];
  const float* gWhh1 = (const float*)d_in[11];
  const float* gbih1 = (const float*)d_in[12];
  const float* gbhh1 = (const float*)d_in[13];
  const float* eWih0 = (const float*)d_in[14];
  const float* eWhh0 = (const float*)d_in[15];
  const float* ebih0 = (const float*)d_in[16];
  const float* ebhh0 = (const float*)d_in[17];
  const float* eWih1 = (const float*)d_in[18];
  const float* eWhh1 = (const float*)d_in[19];
  const float* ebih1 = (const float*)d_in[20];
  const float* ebhh1 = (const float*)d_in[21];
  const float* g2eW  = (const float*)d_in[22];
  const float* g2eb  = (const float*)d_in[23];
  const float* clsW  = (const float*)d_in[24];
  const float* clsb  = (const float*)d_in[25];
  const float* htW   = (const float*)d_in[26];
  const float* htb   = (const float*)d_in[27];
  const float* dtW   = (const float*)d_in[28];
  const float* dtb   = (const float*)d_in[29];

  char* wsb = (char*)d_ws;
  size_t off = 0;
  auto take = [&](size_t bytes)->char* {
    char* p = wsb + off;
    off = (off + bytes + 255) & ~(size_t)255;
    return p;
  };
  bf16*  Xb     = (bf16*) take((size_t)NSEQ*KXP*2);   // 33.6 MB
  bf16*  W0i    = (bf16*) take((size_t)G4*KXP*2);     // interleaved Wih0
  bf16*  W0r    = (bf16*) take((size_t)G4*HG*2);      // interleaved Whh0
  bf16*  W1c    = (bf16*) take((size_t)G4*768*2);     // interleaved [Wih1|Whh1]
  float* gb0i   = (float*)take(G4*4);
  float* gb1i   = (float*)take(G4*4);
  bf16*  G0t    = (bf16*) take((size_t)NSEQ*G4*2);    // 100.7 MB, time-major [t][b][1536]
  bf16*  h0ring = (bf16*) take((size_t)4*BB*HG*2);    // 4-slot h0 exchange ring
  bf16*  h1seq  = (bf16*) take((size_t)NSEQ*HG*2);    // 25.2 MB  [b][t][384]
  unsigned int* flags = (unsigned int*)take(96*16*4); // 96 per-block flag lines x 64B
  bf16*  projb  = (bf16*) take((size_t)NSEQ*HE*2);
  bf16*  eW0b   = (bf16*) take(E4*HE*2);
  bf16*  eW1ab  = (bf16*) take(E4*HE*2);
  bf16*  eW1bb  = (bf16*) take(E4*HE*2);
  float* eb0w   = (float*)take(E4*4);
  float* eb1w   = (float*)take(E4*4);
  float* ew0cw  = (float*)take(E4*4);
  bf16*  g2eWb  = (bf16*) take(HE*HG*2);
  bf16*  htWb   = (bf16*) take(128*HG*2);
  bf16*  dtWb   = (bf16*) take(128*HG*2);

  (void)hipMemsetAsync(d_out, 0, (size_t)16777216*4, stream);
  (void)hipMemsetAsync(flags, 0, 96*16*4, stream);

  prep_x<<<2048,256,0,stream>>>(input, tag, sent, Xb);
  prep_w<<<512,256,0,stream>>>(gWih0,gWhh0,gbih0,gbhh0,gWih1,gWhh1,gbih1,gbhh1,
                               eWih0,eWhh0,ebih0,ebhh0,eWih1,eWhh1,ebih1,ebhh1,
                               g2eW,htW,dtW,
                               W0i,W0r,W1c,gb0i,gb1i,eW0b,eW1ab,eW1bb,
                               eb0w,eb1w,ew0cw,g2eWb,htWb,dtWb);

  // layer-0 input gates, time-major: G0t[t][b][:] = X@W0i^T + gb0
  gemm_mfma<KXP,128,2,2,3><<<3072,256,0,stream>>>(Xb, W0i, gb0i, nullptr, (void*)G0t, G4);

  // persistent 2-layer recurrence (per-block single-writer flags)
  graph_rnn<<<96,256,0,stream>>>(G0t, W0r, W1c, gb1i, h0ring, h1seq, flags);

  // proj = mask * (graph_state @ g2e_W^T) + g2e_b   -> bf16
  gemm_mfma<HG,64,4,1,1><<<256,256,0,stream>>>(h1seq, g2eWb, g2eb, mask, (void*)projb, HE);

  // banded teacher-forced edge LSTM + cls + arc writeback
  edge_lstm<<<2048,256,0,stream>>>(projb, eW0b, eW1ab, eW1bb, eb0w, eb1w, ew0cw,
                                   clsW, clsb, bosp, heads, (float*)d_out);

  // tag feedforwards: elu(mask*(graph_state @ W^T) + b)
  gemm_mfma<HG,128,2,2,2><<<256,256,0,stream>>>(h1seq, htWb, htb, mask,
      (void*)((float*)d_out + 16777216), 100);
  gemm_mfma<HG,128,2,2,2><<<256,256,0,stream>>>(h1seq, dtWb, dtb, mask,
      (void*)((float*)d_out + 16777216 + 3276800), 100);
}